// Round 2
// baseline (2273.810 us; speedup 1.0000x reference)
//
#include <hip/hip_runtime.h>

#define N_NODES 100000
#define EDGES   1600000
#define F_IN    32
#define H_DIM   64
#define C_OUT   10

// ---------------- scatter layer 1: agg1[dst*32 + f] += x[src*32 + f] * w ----
// 8 lanes per edge, each lane handles 4 consecutive floats (float4 gather).
__global__ __launch_bounds__(256) void scatter1_kernel(
    const float4* __restrict__ x4, const int* __restrict__ ei,
    const float* __restrict__ ew, float* __restrict__ agg)
{
    int t = blockIdx.x * 256 + threadIdx.x;
    int e = t >> 3, l = t & 7;
    if (e >= EDGES) return;
    int s = ei[e];            // src row
    int d = ei[EDGES + e];    // dst row
    float w = ew[e];
    float4 v = x4[(size_t)s * 8 + l];
    float* a = agg + (size_t)d * 32 + l * 4;
    atomicAdd(a + 0, v.x * w);
    atomicAdd(a + 1, v.y * w);
    atomicAdd(a + 2, v.z * w);
    atomicAdd(a + 3, v.w * w);
}

// ---------------- scatter layer 2: agg2[dst*64 + f] += h1[src*64 + f] * w ---
// 16 lanes per edge, float4 each.
__global__ __launch_bounds__(256) void scatter2_kernel(
    const float4* __restrict__ h4, const int* __restrict__ ei,
    const float* __restrict__ ew, float* __restrict__ agg)
{
    int t = blockIdx.x * 256 + threadIdx.x;
    int e = t >> 4, l = t & 15;
    if (e >= EDGES) return;
    int s = ei[e];
    int d = ei[EDGES + e];
    float w = ew[e];
    float4 v = h4[(size_t)s * 16 + l];
    float* a = agg + (size_t)d * 64 + l * 4;
    atomicAdd(a + 0, v.x * w);
    atomicAdd(a + 1, v.y * w);
    atomicAdd(a + 2, v.z * w);
    atomicAdd(a + 3, v.w * w);
}

// ---------------- dense 1: h1 = relu(agg1 @ W_rel^T + b + x @ W_root^T) -----
// 4 nodes per 256-thread block; thread (n, h) computes h1[node][h].
__global__ __launch_bounds__(256) void dense1_kernel(
    const float* __restrict__ x, const float* __restrict__ agg,
    const float* __restrict__ W_rel, const float* __restrict__ b_rel,
    const float* __restrict__ W_root, float* __restrict__ h1)
{
    __shared__ float sWrel[64][33];   // +1 pad: lanes vary h at fixed f
    __shared__ float sWroot[64][33];
    __shared__ float sb[64];
    __shared__ float sx[4][32];
    __shared__ float sa[4][32];
    int tid = threadIdx.x;
    for (int i = tid; i < 64 * 32; i += 256) {
        int h = i >> 5, f = i & 31;
        sWrel[h][f]  = W_rel[i];
        sWroot[h][f] = W_root[i];
    }
    if (tid < 64) sb[tid] = b_rel[tid];
    int node0 = blockIdx.x * 4;
    if (tid < 128) {
        int n = tid >> 5, f = tid & 31;
        int node = node0 + n;
        if (node < N_NODES) {
            sx[n][f] = x[(size_t)node * 32 + f];
            sa[n][f] = agg[(size_t)node * 32 + f];
        }
    }
    __syncthreads();
    int n = tid >> 6, h = tid & 63;
    int node = node0 + n;
    if (node >= N_NODES) return;
    float sum = sb[h];
    #pragma unroll
    for (int f = 0; f < 32; ++f)
        sum += sa[n][f] * sWrel[h][f] + sx[n][f] * sWroot[h][f];
    h1[(size_t)node * 64 + h] = fmaxf(sum, 0.f);
}

// ------- dense 2 + fc: out = relu(agg2@W2^T + b2 + h1@W2root^T) @ fc^T + fcb
__global__ __launch_bounds__(256) void dense2fc_kernel(
    const float* __restrict__ h1, const float* __restrict__ agg2,
    const float* __restrict__ W_rel, const float* __restrict__ b_rel,
    const float* __restrict__ W_root,
    const float* __restrict__ fc_w, const float* __restrict__ fc_b,
    float* __restrict__ out)
{
    __shared__ float sWrel[64][65];   // +1 pad
    __shared__ float sWroot[64][65];
    __shared__ float sfc[10][65];
    __shared__ float sb[64], sfb[10];
    __shared__ float sh[4][64], sa[4][64];
    __shared__ float sh2[4][65];
    int tid = threadIdx.x;
    for (int i = tid; i < 64 * 64; i += 256) {
        int h = i >> 6, f = i & 63;
        sWrel[h][f]  = W_rel[i];
        sWroot[h][f] = W_root[i];
    }
    for (int i = tid; i < 10 * 64; i += 256) sfc[i >> 6][i & 63] = fc_w[i];
    if (tid < 64) sb[tid] = b_rel[tid];
    if (tid < 10) sfb[tid] = fc_b[tid];
    int node0 = blockIdx.x * 4;
    {
        int n = tid >> 6, f = tid & 63;
        int node = node0 + n;
        if (node < N_NODES) {
            sh[n][f] = h1[(size_t)node * 64 + f];
            sa[n][f] = agg2[(size_t)node * 64 + f];
        }
    }
    __syncthreads();
    int n = tid >> 6, h = tid & 63;
    int node = node0 + n;
    if (node < N_NODES) {
        float sum = sb[h];
        #pragma unroll
        for (int f = 0; f < 64; ++f)
            sum += sa[n][f] * sWrel[h][f] + sh[n][f] * sWroot[h][f];
        sh2[n][h] = fmaxf(sum, 0.f);
    }
    __syncthreads();
    if (tid < 40) {
        int n2 = tid / 10, c = tid % 10;
        int node = node0 + n2;
        if (node < N_NODES) {
            float o = sfb[c];
            #pragma unroll
            for (int f = 0; f < 64; ++f)
                o += sh2[n2][f] * sfc[c][f];
            out[(size_t)node * 10 + c] = o;
        }
    }
}

extern "C" void kernel_launch(void* const* d_in, const int* in_sizes, int n_in,
                              void* d_out, int out_size, void* d_ws, size_t ws_size,
                              hipStream_t stream) {
    const float* x       = (const float*)d_in[0];
    const int*   ei      = (const int*)d_in[1];     // [2, E] int32 (JAX x64 off)
    const float* ew      = (const float*)d_in[2];
    const float* W1_rel  = (const float*)d_in[3];
    const float* b1_rel  = (const float*)d_in[4];
    const float* W1_root = (const float*)d_in[5];
    const float* W2_rel  = (const float*)d_in[6];
    const float* b2_rel  = (const float*)d_in[7];
    const float* W2_root = (const float*)d_in[8];
    const float* fc_w    = (const float*)d_in[9];
    const float* fc_b    = (const float*)d_in[10];
    float* out = (float*)d_out;

    float* agg1 = (float*)d_ws;                         // N*32
    float* agg2 = agg1 + (size_t)N_NODES * 32;          // N*64
    float* h1   = agg2 + (size_t)N_NODES * 64;          // N*64

    // agg buffers must be zeroed every call (ws re-poisoned 0xAA).
    hipMemsetAsync(d_ws, 0, (size_t)N_NODES * 96 * sizeof(float), stream);

    scatter1_kernel<<<(EDGES * 8 + 255) / 256, 256, 0, stream>>>(
        (const float4*)x, ei, ew, agg1);
    dense1_kernel<<<(N_NODES + 3) / 4, 256, 0, stream>>>(
        x, agg1, W1_rel, b1_rel, W1_root, h1);
    scatter2_kernel<<<(EDGES * 16 + 255) / 256, 256, 0, stream>>>(
        (const float4*)h1, ei, ew, agg2);
    dense2fc_kernel<<<(N_NODES + 3) / 4, 256, 0, stream>>>(
        h1, agg2, W2_rel, b2_rel, W2_root, fc_w, fc_b, out);
}

// Round 3
// 695.668 us; speedup vs baseline: 3.2685x; 3.2685x over previous
//
#include <hip/hip_runtime.h>

#define N_NODES 100000
#define EDGES   1600000
#define F_IN    32
#define H_DIM   64
#define C_OUT   10
#define SCAN_NB ((N_NODES + 511) / 512)   // 196 scan blocks

// ---------------- CSR build: histogram of dst ------------------------------
__global__ __launch_bounds__(256) void hist_kernel(
    const int* __restrict__ ei, int* __restrict__ cnt)
{
    int e = blockIdx.x * 256 + threadIdx.x;
    if (e >= EDGES) return;
    atomicAdd(&cnt[ei[EDGES + e]], 1);
}

// ---------------- exclusive scan over cnt[N] (3 kernels) -------------------
__global__ __launch_bounds__(512) void scan1_kernel(
    const int* __restrict__ cnt, int* __restrict__ part, int* __restrict__ bsum)
{
    __shared__ int s[512];
    int tid = threadIdx.x;
    int gid = blockIdx.x * 512 + tid;
    int v = (gid < N_NODES) ? cnt[gid] : 0;
    s[tid] = v;
    __syncthreads();
    for (int off = 1; off < 512; off <<= 1) {
        int t = (tid >= off) ? s[tid - off] : 0;
        __syncthreads();
        s[tid] += t;
        __syncthreads();
    }
    if (gid < N_NODES) part[gid] = s[tid] - v;        // exclusive within block
    if (tid == 511) bsum[blockIdx.x] = s[511];        // block total
}

__global__ __launch_bounds__(256) void scan2_kernel(
    const int* __restrict__ bsum, int* __restrict__ bsumx)
{
    __shared__ int s[256];
    int tid = threadIdx.x;
    int v = (tid < SCAN_NB) ? bsum[tid] : 0;
    s[tid] = v;
    __syncthreads();
    for (int off = 1; off < 256; off <<= 1) {
        int t = (tid >= off) ? s[tid - off] : 0;
        __syncthreads();
        s[tid] += t;
        __syncthreads();
    }
    bsumx[tid] = s[tid] - v;                          // exclusive block offsets
}

__global__ __launch_bounds__(512) void scan3_kernel(
    const int* __restrict__ part, const int* __restrict__ bsumx,
    int* __restrict__ offs, int* __restrict__ cursor)
{
    int gid = blockIdx.x * 512 + threadIdx.x;
    if (gid < N_NODES) {
        int o = part[gid] + bsumx[blockIdx.x];
        offs[gid] = o;
        cursor[gid] = o;
    }
    if (gid == 0) offs[N_NODES] = EDGES;
}

// ---------------- CSR fill: bucket[pos] = (src, weight) --------------------
__global__ __launch_bounds__(256) void fill_kernel(
    const int* __restrict__ ei, const float* __restrict__ ew,
    int* __restrict__ cursor, uint2* __restrict__ bucket)
{
    int e = blockIdx.x * 256 + threadIdx.x;
    if (e >= EDGES) return;
    int d = ei[EDGES + e];
    int pos = atomicAdd(&cursor[d], 1);
    uint2 slot;
    slot.x = (unsigned)ei[e];
    slot.y = __float_as_uint(ew[e]);
    bucket[pos] = slot;
}

// ------- fused layer 1: gather-agg (32 lanes/node) + dense + relu ----------
#define K1_NPB 8
__global__ __launch_bounds__(256) void agg_dense1_kernel(
    const float* __restrict__ x, const uint2* __restrict__ bucket,
    const int* __restrict__ offs,
    const float* __restrict__ W_rel, const float* __restrict__ b_rel,
    const float* __restrict__ W_root, float* __restrict__ h1)
{
    __shared__ float sWrel[64][33];   // +1 pad: phase-B lanes vary h, stride 33
    __shared__ float sWroot[64][33];
    __shared__ float sb[64];
    __shared__ float sagg[K1_NPB][33];
    __shared__ float sx[K1_NPB][33];
    int tid = threadIdx.x;
    for (int i = tid; i < 64 * 32; i += 256) {
        sWrel[i >> 5][i & 31]  = W_rel[i];
        sWroot[i >> 5][i & 31] = W_root[i];
    }
    if (tid < 64) sb[tid] = b_rel[tid];
    int g = tid >> 5, f = tid & 31;    // phase A: 8 groups x 32 lanes
    int n4 = tid >> 6, h = tid & 63;   // phase B: 4 (node,h) pairs

    for (int base = blockIdx.x * K1_NPB; base < N_NODES; base += gridDim.x * K1_NPB) {
        __syncthreads();               // LDS reuse guard (and weight visibility)
        // phase A: gather-aggregate, zero atomics
        {
            int node = base + g;
            float acc = 0.f, xv = 0.f;
            if (node < N_NODES) {
                xv = x[(size_t)node * 32 + f];
                int o0 = offs[node], o1 = offs[node + 1];
                for (int j = o0; j < o1; ++j) {
                    uint2 slot = bucket[j];                  // group-uniform load
                    acc += x[(size_t)slot.x * 32 + f] * __uint_as_float(slot.y);
                }
            }
            sagg[g][f] = acc;
            sx[g][f] = xv;
        }
        __syncthreads();
        // phase B: h1 = relu(agg @ Wrel^T + b + x @ Wroot^T)
        for (int ni = 0; ni < 2; ++ni) {
            int nn = ni * 4 + n4;
            int node = base + nn;
            if (node < N_NODES) {
                float sum = sb[h];
                #pragma unroll
                for (int ff = 0; ff < 32; ++ff)
                    sum += sagg[nn][ff] * sWrel[h][ff] + sx[nn][ff] * sWroot[h][ff];
                h1[(size_t)node * 64 + h] = fmaxf(sum, 0.f);
            }
        }
    }
}

// ------- fused layer 2: gather-agg (64 lanes/node) + dense + relu + fc -----
#define K2_NPB 4
__global__ __launch_bounds__(256) void agg_dense2_kernel(
    const float* __restrict__ h1, const uint2* __restrict__ bucket,
    const int* __restrict__ offs,
    const float* __restrict__ W_rel, const float* __restrict__ b_rel,
    const float* __restrict__ W_root,
    const float* __restrict__ fc_w, const float* __restrict__ fc_b,
    float* __restrict__ out)
{
    __shared__ float sWrel[64][65];   // +1 pad
    __shared__ float sWroot[64][65];
    __shared__ float sfc[10][65];
    __shared__ float sb[64], sfb[10];
    __shared__ float sagg[K2_NPB][65];
    __shared__ float sh[K2_NPB][65];
    __shared__ float sh2[K2_NPB][65];
    int tid = threadIdx.x;
    for (int i = tid; i < 64 * 64; i += 256) {
        sWrel[i >> 6][i & 63]  = W_rel[i];
        sWroot[i >> 6][i & 63] = W_root[i];
    }
    for (int i = tid; i < 10 * 64; i += 256) sfc[i >> 6][i & 63] = fc_w[i];
    if (tid < 64) sb[tid] = b_rel[tid];
    if (tid < 10) sfb[tid] = fc_b[tid];
    int g = tid >> 6, f = tid & 63;    // 4 groups x 64 lanes (1 wave/node)

    for (int base = blockIdx.x * K2_NPB; base < N_NODES; base += gridDim.x * K2_NPB) {
        __syncthreads();               // LDS reuse guard
        // phase A: gather-aggregate
        {
            int node = base + g;
            float acc = 0.f, hv = 0.f;
            if (node < N_NODES) {
                hv = h1[(size_t)node * 64 + f];
                int o0 = offs[node], o1 = offs[node + 1];
                for (int j = o0; j < o1; ++j) {
                    uint2 slot = bucket[j];                  // wave-uniform load
                    acc += h1[(size_t)slot.x * 64 + f] * __uint_as_float(slot.y);
                }
            }
            sagg[g][f] = acc;
            sh[g][f] = hv;
        }
        __syncthreads();
        // phase B: relu dense (thread (g,f) -> node g, output h=f)
        {
            float sum = sb[f];
            #pragma unroll
            for (int ff = 0; ff < 64; ++ff)
                sum += sagg[g][ff] * sWrel[f][ff] + sh[g][ff] * sWroot[f][ff];
            sh2[g][f] = fmaxf(sum, 0.f);
        }
        __syncthreads();
        // phase C: fc (40 threads)
        if (tid < 4 * 10) {
            int n2 = tid / 10, c = tid % 10;
            int node = base + n2;
            if (node < N_NODES) {
                float o = sfb[c];
                #pragma unroll
                for (int ff = 0; ff < 64; ++ff)
                    o += sh2[n2][ff] * sfc[c][ff];
                out[(size_t)node * 10 + c] = o;
            }
        }
    }
}

extern "C" void kernel_launch(void* const* d_in, const int* in_sizes, int n_in,
                              void* d_out, int out_size, void* d_ws, size_t ws_size,
                              hipStream_t stream) {
    const float* x       = (const float*)d_in[0];
    const int*   ei      = (const int*)d_in[1];     // [2, E] int32
    const float* ew      = (const float*)d_in[2];
    const float* W1_rel  = (const float*)d_in[3];
    const float* b1_rel  = (const float*)d_in[4];
    const float* W1_root = (const float*)d_in[5];
    const float* W2_rel  = (const float*)d_in[6];
    const float* b2_rel  = (const float*)d_in[7];
    const float* W2_root = (const float*)d_in[8];
    const float* fc_w    = (const float*)d_in[9];
    const float* fc_b    = (const float*)d_in[10];
    float* out = (float*)d_out;

    // workspace layout (~40 MB)
    uint2* bucket = (uint2*)d_ws;                       // E slots (12.8 MB)
    float* h1     = (float*)(bucket + EDGES);           // N*64   (25.6 MB)
    int*   cnt    = (int*)(h1 + (size_t)N_NODES * 64);  // N
    int*   part   = cnt + N_NODES;                      // N
    int*   offs   = part + N_NODES;                     // N+1
    int*   cursor = offs + N_NODES + 1;                 // N
    int*   bsum   = cursor + N_NODES;                   // 256
    int*   bsumx  = bsum + 256;                         // 256

    // only the histogram counters need zeroing (ws re-poisoned 0xAA each call)
    hipMemsetAsync(cnt, 0, (size_t)N_NODES * sizeof(int), stream);

    hist_kernel<<<(EDGES + 255) / 256, 256, 0, stream>>>(ei, cnt);
    scan1_kernel<<<SCAN_NB, 512, 0, stream>>>(cnt, part, bsum);
    scan2_kernel<<<1, 256, 0, stream>>>(bsum, bsumx);
    scan3_kernel<<<SCAN_NB, 512, 0, stream>>>(part, bsumx, offs, cursor);
    fill_kernel<<<(EDGES + 255) / 256, 256, 0, stream>>>(ei, ew, cursor, bucket);

    agg_dense1_kernel<<<2048, 256, 0, stream>>>(
        x, bucket, offs, W1_rel, b1_rel, W1_root, h1);
    agg_dense2_kernel<<<2048, 256, 0, stream>>>(
        h1, bucket, offs, W2_rel, b2_rel, W2_root, fc_w, fc_b, out);
}

// Round 8
// 502.614 us; speedup vs baseline: 4.5240x; 1.3841x over previous
//
#include <hip/hip_runtime.h>

#define N_NODES 100000
#define EDGES   1600000
#define F_IN    32
#define H_DIM   64
#define C_OUT   10
#define SCAN_NB ((N_NODES + 511) / 512)   // 196 scan blocks

// ---------------- CSR build: histogram of dst ------------------------------
__global__ __launch_bounds__(256) void hist_kernel(
    const int* __restrict__ ei, int* __restrict__ cnt)
{
    int e = blockIdx.x * 256 + threadIdx.x;
    if (e >= EDGES) return;
    atomicAdd(&cnt[ei[EDGES + e]], 1);
}

// ---------------- exclusive scan over cnt[N] (3 kernels) -------------------
__global__ __launch_bounds__(512) void scan1_kernel(
    const int* __restrict__ cnt, int* __restrict__ part, int* __restrict__ bsum)
{
    __shared__ int s[512];
    int tid = threadIdx.x;
    int gid = blockIdx.x * 512 + tid;
    int v = (gid < N_NODES) ? cnt[gid] : 0;
    s[tid] = v;
    __syncthreads();
    for (int off = 1; off < 512; off <<= 1) {
        int t = (tid >= off) ? s[tid - off] : 0;
        __syncthreads();
        s[tid] += t;
        __syncthreads();
    }
    if (gid < N_NODES) part[gid] = s[tid] - v;        // exclusive within block
    if (tid == 511) bsum[blockIdx.x] = s[511];        // block total
}

__global__ __launch_bounds__(256) void scan2_kernel(
    const int* __restrict__ bsum, int* __restrict__ bsumx)
{
    __shared__ int s[256];
    int tid = threadIdx.x;
    int v = (tid < SCAN_NB) ? bsum[tid] : 0;
    s[tid] = v;
    __syncthreads();
    for (int off = 1; off < 256; off <<= 1) {
        int t = (tid >= off) ? s[tid - off] : 0;
        __syncthreads();
        s[tid] += t;
        __syncthreads();
    }
    bsumx[tid] = s[tid] - v;                          // exclusive block offsets
}

__global__ __launch_bounds__(512) void scan3_kernel(
    const int* __restrict__ part, const int* __restrict__ bsumx,
    int* __restrict__ offs, int* __restrict__ cursor)
{
    int gid = blockIdx.x * 512 + threadIdx.x;
    if (gid < N_NODES) {
        int o = part[gid] + bsumx[blockIdx.x];
        offs[gid] = o;
        cursor[gid] = o;
    }
    if (gid == 0) offs[N_NODES] = EDGES;
}

// ---------------- CSR fill: bucket[pos] = (src, weight) --------------------
__global__ __launch_bounds__(256) void fill_kernel(
    const int* __restrict__ ei, const float* __restrict__ ew,
    int* __restrict__ cursor, uint2* __restrict__ bucket)
{
    int e = blockIdx.x * 256 + threadIdx.x;
    if (e >= EDGES) return;
    int d = ei[EDGES + e];
    int pos = atomicAdd(&cursor[d], 1);
    uint2 slot;
    slot.x = (unsigned)ei[e];
    slot.y = __float_as_uint(ew[e]);
    bucket[pos] = slot;
}

// ------- fused layer 1: gather-agg (32 lanes/node) + dense + relu ----------
#define K1_NPB 8
__global__ __launch_bounds__(256) void agg_dense1_kernel(
    const float* __restrict__ x, const uint2* __restrict__ bucket,
    const int* __restrict__ offs,
    const float* __restrict__ W_rel, const float* __restrict__ b_rel,
    const float* __restrict__ W_root, float* __restrict__ h1)
{
    __shared__ float sWrel[64][33];   // +1 pad: phase-B lanes vary h, stride 33
    __shared__ float sWroot[64][33];
    __shared__ float sb[64];
    __shared__ float sagg[K1_NPB][33];
    __shared__ float sx[K1_NPB][33];
    int tid = threadIdx.x;
    for (int i = tid; i < 64 * 32; i += 256) {
        sWrel[i >> 5][i & 31]  = W_rel[i];
        sWroot[i >> 5][i & 31] = W_root[i];
    }
    if (tid < 64) sb[tid] = b_rel[tid];
    int g = tid >> 5, f = tid & 31;    // phase A: 8 groups x 32 lanes
    int n4 = tid >> 6, h = tid & 63;   // phase B: 4 (node,h) pairs

    for (int base = blockIdx.x * K1_NPB; base < N_NODES; base += gridDim.x * K1_NPB) {
        __syncthreads();               // LDS reuse guard (and weight visibility)
        // phase A: gather-aggregate, zero atomics, 4-deep MLP unroll
        {
            int node = base + g;
            float acc = 0.f, xv = 0.f;
            if (node < N_NODES) {
                xv = x[(size_t)node * 32 + f];
                int o0 = offs[node], o1 = offs[node + 1];
                int j = o0;
                for (; j + 4 <= o1; j += 4) {
                    uint2 s0 = bucket[j + 0];
                    uint2 s1 = bucket[j + 1];
                    uint2 s2 = bucket[j + 2];
                    uint2 s3 = bucket[j + 3];
                    float v0 = x[(size_t)s0.x * 32 + f];
                    float v1 = x[(size_t)s1.x * 32 + f];
                    float v2 = x[(size_t)s2.x * 32 + f];
                    float v3 = x[(size_t)s3.x * 32 + f];
                    acc += v0 * __uint_as_float(s0.y) + v1 * __uint_as_float(s1.y)
                         + v2 * __uint_as_float(s2.y) + v3 * __uint_as_float(s3.y);
                }
                for (; j < o1; ++j) {
                    uint2 s = bucket[j];
                    acc += x[(size_t)s.x * 32 + f] * __uint_as_float(s.y);
                }
            }
            sagg[g][f] = acc;
            sx[g][f] = xv;
        }
        __syncthreads();
        // phase B: h1 = relu(agg @ Wrel^T + b + x @ Wroot^T)
        for (int ni = 0; ni < 2; ++ni) {
            int nn = ni * 4 + n4;
            int node = base + nn;
            if (node < N_NODES) {
                float sum = sb[h];
                #pragma unroll
                for (int ff = 0; ff < 32; ++ff)
                    sum += sagg[nn][ff] * sWrel[h][ff] + sx[nn][ff] * sWroot[h][ff];
                h1[(size_t)node * 64 + h] = fmaxf(sum, 0.f);
            }
        }
    }
}

// ------- fused layer 2: gather-agg (64 lanes/node) + dense + relu + fc -----
#define K2_NPB 4
__global__ __launch_bounds__(256) void agg_dense2_kernel(
    const float* __restrict__ h1, const uint2* __restrict__ bucket,
    const int* __restrict__ offs,
    const float* __restrict__ W_rel, const float* __restrict__ b_rel,
    const float* __restrict__ W_root,
    const float* __restrict__ fc_w, const float* __restrict__ fc_b,
    float* __restrict__ out)
{
    __shared__ float sWrel[64][65];   // +1 pad
    __shared__ float sWroot[64][65];
    __shared__ float sfc[10][65];
    __shared__ float sb[64], sfb[10];
    __shared__ float sagg[K2_NPB][65];
    __shared__ float sh[K2_NPB][65];
    __shared__ float sh2[K2_NPB][65];
    int tid = threadIdx.x;
    for (int i = tid; i < 64 * 64; i += 256) {
        sWrel[i >> 6][i & 63]  = W_rel[i];
        sWroot[i >> 6][i & 63] = W_root[i];
    }
    for (int i = tid; i < 10 * 64; i += 256) sfc[i >> 6][i & 63] = fc_w[i];
    if (tid < 64) sb[tid] = b_rel[tid];
    if (tid < 10) sfb[tid] = fc_b[tid];
    int g = tid >> 6, f = tid & 63;    // 4 groups x 64 lanes (1 wave/node)

    for (int base = blockIdx.x * K2_NPB; base < N_NODES; base += gridDim.x * K2_NPB) {
        __syncthreads();               // LDS reuse guard
        // phase A: gather-aggregate, wave-uniform bounds in SGPRs, MLP unroll
        {
            int node = base + g;
            float acc = 0.f, hv = 0.f;
            if (node < N_NODES) {
                hv = h1[(size_t)node * 64 + f];
                int o0 = __builtin_amdgcn_readfirstlane(offs[node]);
                int o1 = __builtin_amdgcn_readfirstlane(offs[node + 1]);
                int j = o0;
                for (; j + 4 <= o1; j += 4) {
                    uint2 s0 = bucket[j + 0];
                    uint2 s1 = bucket[j + 1];
                    uint2 s2 = bucket[j + 2];
                    uint2 s3 = bucket[j + 3];
                    float v0 = h1[(size_t)s0.x * 64 + f];
                    float v1 = h1[(size_t)s1.x * 64 + f];
                    float v2 = h1[(size_t)s2.x * 64 + f];
                    float v3 = h1[(size_t)s3.x * 64 + f];
                    acc += v0 * __uint_as_float(s0.y) + v1 * __uint_as_float(s1.y)
                         + v2 * __uint_as_float(s2.y) + v3 * __uint_as_float(s3.y);
                }
                for (; j < o1; ++j) {
                    uint2 s = bucket[j];
                    acc += h1[(size_t)s.x * 64 + f] * __uint_as_float(s.y);
                }
            }
            sagg[g][f] = acc;
            sh[g][f] = hv;
        }
        __syncthreads();
        // phase B: relu dense (thread (g,f) -> node g, output h=f)
        {
            float sum = sb[f];
            #pragma unroll
            for (int ff = 0; ff < 64; ++ff)
                sum += sagg[g][ff] * sWrel[f][ff] + sh[g][ff] * sWroot[f][ff];
            sh2[g][f] = fmaxf(sum, 0.f);
        }
        __syncthreads();
        // phase C: fc (40 threads)
        if (tid < 4 * 10) {
            int n2 = tid / 10, c = tid % 10;
            int node = base + n2;
            if (node < N_NODES) {
                float o = sfb[c];
                #pragma unroll
                for (int ff = 0; ff < 64; ++ff)
                    o += sh2[n2][ff] * sfc[c][ff];
                out[(size_t)node * 10 + c] = o;
            }
        }
    }
}

extern "C" void kernel_launch(void* const* d_in, const int* in_sizes, int n_in,
                              void* d_out, int out_size, void* d_ws, size_t ws_size,
                              hipStream_t stream) {
    const float* x       = (const float*)d_in[0];
    const int*   ei      = (const int*)d_in[1];     // [2, E] int32
    const float* ew      = (const float*)d_in[2];
    const float* W1_rel  = (const float*)d_in[3];
    const float* b1_rel  = (const float*)d_in[4];
    const float* W1_root = (const float*)d_in[5];
    const float* W2_rel  = (const float*)d_in[6];
    const float* b2_rel  = (const float*)d_in[7];
    const float* W2_root = (const float*)d_in[8];
    const float* fc_w    = (const float*)d_in[9];
    const float* fc_b    = (const float*)d_in[10];
    float* out = (float*)d_out;

    // workspace layout (~40 MB)
    uint2* bucket = (uint2*)d_ws;                       // E slots (12.8 MB)
    float* h1     = (float*)(bucket + EDGES);           // N*64   (25.6 MB)
    int*   cnt    = (int*)(h1 + (size_t)N_NODES * 64);  // N
    int*   part   = cnt + N_NODES;                      // N
    int*   offs   = part + N_NODES;                     // N+1
    int*   cursor = offs + N_NODES + 1;                 // N
    int*   bsum   = cursor + N_NODES;                   // 256
    int*   bsumx  = bsum + 256;                         // 256

    // only the histogram counters need zeroing (ws re-poisoned 0xAA each call)
    hipMemsetAsync(cnt, 0, (size_t)N_NODES * sizeof(int), stream);

    hist_kernel<<<(EDGES + 255) / 256, 256, 0, stream>>>(ei, cnt);
    scan1_kernel<<<SCAN_NB, 512, 0, stream>>>(cnt, part, bsum);
    scan2_kernel<<<1, 256, 0, stream>>>(bsum, bsumx);
    scan3_kernel<<<SCAN_NB, 512, 0, stream>>>(part, bsumx, offs, cursor);
    fill_kernel<<<(EDGES + 255) / 256, 256, 0, stream>>>(ei, ew, cursor, bucket);

    agg_dense1_kernel<<<2048, 256, 0, stream>>>(
        x, bucket, offs, W1_rel, b1_rel, W1_root, h1);
    agg_dense2_kernel<<<2048, 256, 0, stream>>>(
        h1, bucket, offs, W2_rel, b2_rel, W2_root, fc_w, fc_b, out);
}

// Round 10
// 459.205 us; speedup vs baseline: 4.9516x; 1.0945x over previous
//
#include <hip/hip_runtime.h>

#define N_NODES 100000
#define EDGES   1600000
#define F_IN    32
#define H_DIM   64
#define C_OUT   10
#define SCAN_NB ((N_NODES + 511) / 512)   // 196 scan blocks

// ---- bf16 helpers (round-half-up via +0x8000; adequate vs 0.59 threshold) --
__device__ __forceinline__ unsigned pack_bf16(float a, float b) {
    unsigned ua = (__float_as_uint(a) + 0x8000u) >> 16;
    unsigned ub = (__float_as_uint(b) + 0x8000u) & 0xffff0000u;
    return ub | ua;
}
__device__ __forceinline__ float bflo(unsigned p) { return __uint_as_float(p << 16); }
__device__ __forceinline__ float bfhi(unsigned p) { return __uint_as_float(p & 0xffff0000u); }
__device__ __forceinline__ float bf2f(unsigned short u) { return __uint_as_float(((unsigned)u) << 16); }
__device__ __forceinline__ unsigned short f2bf(float x) { return (unsigned short)((__float_as_uint(x) + 0x8000u) >> 16); }

// ---------------- CSR build: histogram of dst ------------------------------
__global__ __launch_bounds__(256) void hist_kernel(
    const int* __restrict__ ei, int* __restrict__ cnt)
{
    int e = blockIdx.x * 256 + threadIdx.x;
    if (e >= EDGES) return;
    atomicAdd(&cnt[ei[EDGES + e]], 1);
}

// ---------------- exclusive scan over cnt[N] (3 kernels) -------------------
__global__ __launch_bounds__(512) void scan1_kernel(
    const int* __restrict__ cnt, int* __restrict__ part, int* __restrict__ bsum)
{
    __shared__ int s[512];
    int tid = threadIdx.x;
    int gid = blockIdx.x * 512 + tid;
    int v = (gid < N_NODES) ? cnt[gid] : 0;
    s[tid] = v;
    __syncthreads();
    for (int off = 1; off < 512; off <<= 1) {
        int t = (tid >= off) ? s[tid - off] : 0;
        __syncthreads();
        s[tid] += t;
        __syncthreads();
    }
    if (gid < N_NODES) part[gid] = s[tid] - v;        // exclusive within block
    if (tid == 511) bsum[blockIdx.x] = s[511];        // block total
}

__global__ __launch_bounds__(256) void scan2_kernel(
    const int* __restrict__ bsum, int* __restrict__ bsumx)
{
    __shared__ int s[256];
    int tid = threadIdx.x;
    int v = (tid < SCAN_NB) ? bsum[tid] : 0;
    s[tid] = v;
    __syncthreads();
    for (int off = 1; off < 256; off <<= 1) {
        int t = (tid >= off) ? s[tid - off] : 0;
        __syncthreads();
        s[tid] += t;
        __syncthreads();
    }
    bsumx[tid] = s[tid] - v;                          // exclusive block offsets
}

__global__ __launch_bounds__(512) void scan3_kernel(
    const int* __restrict__ part, const int* __restrict__ bsumx,
    int* __restrict__ offs, int* __restrict__ cursor)
{
    int gid = blockIdx.x * 512 + threadIdx.x;
    if (gid < N_NODES) {
        int o = part[gid] + bsumx[blockIdx.x];
        offs[gid] = o;
        cursor[gid] = o;
    }
    if (gid == 0) offs[N_NODES] = EDGES;
}

// ---------------- CSR fill: bucket[pos] = (src, weight) --------------------
__global__ __launch_bounds__(256) void fill_kernel(
    const int* __restrict__ ei, const float* __restrict__ ew,
    int* __restrict__ cursor, uint2* __restrict__ bucket)
{
    int e = blockIdx.x * 256 + threadIdx.x;
    if (e >= EDGES) return;
    int d = ei[EDGES + e];
    int pos = atomicAdd(&cursor[d], 1);
    uint2 slot;
    slot.x = (unsigned)ei[e];
    slot.y = __float_as_uint(ew[e]);
    bucket[pos] = slot;
}

// ------- fused layer 1: gather-agg (32 lanes/node) + dense + relu ----------
// weights packed bf16 in LDS; h1 written as bf16; 8-deep MLP unroll.
#define K1_NPB 8
__global__ __launch_bounds__(256, 6) void agg_dense1_kernel(
    const float* __restrict__ x, const uint2* __restrict__ bucket,
    const int* __restrict__ offs,
    const float* __restrict__ W_rel, const float* __restrict__ b_rel,
    const float* __restrict__ W_root, unsigned short* __restrict__ h1b)
{
    __shared__ unsigned sWrel[64][17];   // packed bf16 pairs; banks (17h+k)%32 conflict-free
    __shared__ unsigned sWroot[64][17];
    __shared__ float sb[64];
    __shared__ float sagg[K1_NPB][33];
    __shared__ float sx[K1_NPB][33];
    int tid = threadIdx.x;
    for (int i = tid; i < 64 * 16; i += 256) {
        int h = i >> 4, k = i & 15;
        sWrel[h][k]  = pack_bf16(W_rel[h * 32 + 2 * k],  W_rel[h * 32 + 2 * k + 1]);
        sWroot[h][k] = pack_bf16(W_root[h * 32 + 2 * k], W_root[h * 32 + 2 * k + 1]);
    }
    if (tid < 64) sb[tid] = b_rel[tid];
    int g = tid >> 5, f = tid & 31;    // phase A: 8 groups x 32 lanes
    int n4 = tid >> 6, h = tid & 63;   // phase B: 4 (node,h) pairs

    for (int base = blockIdx.x * K1_NPB; base < N_NODES; base += gridDim.x * K1_NPB) {
        __syncthreads();               // LDS reuse guard (and weight visibility)
        // phase A: gather-aggregate, 8-deep MLP
        {
            int node = base + g;
            float acc = 0.f, xv = 0.f;
            if (node < N_NODES) {
                xv = x[(size_t)node * 32 + f];
                int o0 = offs[node], o1 = offs[node + 1];
                int j = o0;
                for (; j + 8 <= o1; j += 8) {
                    uint2 s0 = bucket[j + 0], s1 = bucket[j + 1];
                    uint2 s2 = bucket[j + 2], s3 = bucket[j + 3];
                    uint2 s4 = bucket[j + 4], s5 = bucket[j + 5];
                    uint2 s6 = bucket[j + 6], s7 = bucket[j + 7];
                    float v0 = x[(size_t)s0.x * 32 + f];
                    float v1 = x[(size_t)s1.x * 32 + f];
                    float v2 = x[(size_t)s2.x * 32 + f];
                    float v3 = x[(size_t)s3.x * 32 + f];
                    float v4 = x[(size_t)s4.x * 32 + f];
                    float v5 = x[(size_t)s5.x * 32 + f];
                    float v6 = x[(size_t)s6.x * 32 + f];
                    float v7 = x[(size_t)s7.x * 32 + f];
                    acc += v0 * __uint_as_float(s0.y) + v1 * __uint_as_float(s1.y)
                         + v2 * __uint_as_float(s2.y) + v3 * __uint_as_float(s3.y)
                         + v4 * __uint_as_float(s4.y) + v5 * __uint_as_float(s5.y)
                         + v6 * __uint_as_float(s6.y) + v7 * __uint_as_float(s7.y);
                }
                for (; j + 4 <= o1; j += 4) {
                    uint2 s0 = bucket[j + 0], s1 = bucket[j + 1];
                    uint2 s2 = bucket[j + 2], s3 = bucket[j + 3];
                    float v0 = x[(size_t)s0.x * 32 + f];
                    float v1 = x[(size_t)s1.x * 32 + f];
                    float v2 = x[(size_t)s2.x * 32 + f];
                    float v3 = x[(size_t)s3.x * 32 + f];
                    acc += v0 * __uint_as_float(s0.y) + v1 * __uint_as_float(s1.y)
                         + v2 * __uint_as_float(s2.y) + v3 * __uint_as_float(s3.y);
                }
                for (; j < o1; ++j) {
                    uint2 s = bucket[j];
                    acc += x[(size_t)s.x * 32 + f] * __uint_as_float(s.y);
                }
            }
            sagg[g][f] = acc;
            sx[g][f] = xv;
        }
        __syncthreads();
        // phase B: h1 = relu(agg @ Wrel^T + b + x @ Wroot^T) -> bf16 store
        for (int ni = 0; ni < 2; ++ni) {
            int nn = ni * 4 + n4;
            int node = base + nn;
            if (node < N_NODES) {
                float sum = sb[h];
                #pragma unroll
                for (int k = 0; k < 16; ++k) {
                    unsigned pr = sWrel[h][k], po = sWroot[h][k];
                    sum += sagg[nn][2 * k]     * bflo(pr)
                         + sagg[nn][2 * k + 1] * bfhi(pr)
                         + sx[nn][2 * k]       * bflo(po)
                         + sx[nn][2 * k + 1]   * bfhi(po);
                }
                h1b[(size_t)node * 64 + h] = f2bf(fmaxf(sum, 0.f));
            }
        }
    }
}

// ------- fused layer 2: gather-agg (64 lanes/node, bf16 h1) + dense + fc ---
#define K2_NPB 4
__global__ __launch_bounds__(256, 6) void agg_dense2_kernel(
    const unsigned short* __restrict__ h1b, const uint2* __restrict__ bucket,
    const int* __restrict__ offs,
    const float* __restrict__ W_rel, const float* __restrict__ b_rel,
    const float* __restrict__ W_root,
    const float* __restrict__ fc_w, const float* __restrict__ fc_b,
    float* __restrict__ out)
{
    __shared__ unsigned sWrel[64][33];   // packed bf16 pairs; banks (33f+k)%32=(f+k)%32
    __shared__ unsigned sWroot[64][33];
    __shared__ unsigned sfc[10][33];
    __shared__ float sb[64], sfb[10];
    __shared__ float sagg[K2_NPB][65];
    __shared__ float sh[K2_NPB][65];
    __shared__ float sh2[K2_NPB][65];
    int tid = threadIdx.x;
    for (int i = tid; i < 64 * 32; i += 256) {
        int h = i >> 5, k = i & 31;
        sWrel[h][k]  = pack_bf16(W_rel[h * 64 + 2 * k],  W_rel[h * 64 + 2 * k + 1]);
        sWroot[h][k] = pack_bf16(W_root[h * 64 + 2 * k], W_root[h * 64 + 2 * k + 1]);
    }
    for (int i = tid; i < 10 * 32; i += 256) {
        int c = i >> 5, k = i & 31;
        sfc[c][k] = pack_bf16(fc_w[c * 64 + 2 * k], fc_w[c * 64 + 2 * k + 1]);
    }
    if (tid < 64) sb[tid] = b_rel[tid];
    if (tid < 10) sfb[tid] = fc_b[tid];
    int g = tid >> 6, f = tid & 63;    // 4 waves, 1 node/wave

    for (int base = blockIdx.x * K2_NPB; base < N_NODES; base += gridDim.x * K2_NPB) {
        __syncthreads();               // LDS reuse guard
        // phase A: gather-aggregate over bf16 h1, 8-deep MLP, SGPR bounds
        {
            int node = base + g;
            float acc = 0.f, hv = 0.f;
            if (node < N_NODES) {
                hv = bf2f(h1b[(size_t)node * 64 + f]);
                int o0 = __builtin_amdgcn_readfirstlane(offs[node]);
                int o1 = __builtin_amdgcn_readfirstlane(offs[node + 1]);
                int j = o0;
                for (; j + 8 <= o1; j += 8) {
                    uint2 s0 = bucket[j + 0], s1 = bucket[j + 1];
                    uint2 s2 = bucket[j + 2], s3 = bucket[j + 3];
                    uint2 s4 = bucket[j + 4], s5 = bucket[j + 5];
                    uint2 s6 = bucket[j + 6], s7 = bucket[j + 7];
                    float v0 = bf2f(h1b[(size_t)s0.x * 64 + f]);
                    float v1 = bf2f(h1b[(size_t)s1.x * 64 + f]);
                    float v2 = bf2f(h1b[(size_t)s2.x * 64 + f]);
                    float v3 = bf2f(h1b[(size_t)s3.x * 64 + f]);
                    float v4 = bf2f(h1b[(size_t)s4.x * 64 + f]);
                    float v5 = bf2f(h1b[(size_t)s5.x * 64 + f]);
                    float v6 = bf2f(h1b[(size_t)s6.x * 64 + f]);
                    float v7 = bf2f(h1b[(size_t)s7.x * 64 + f]);
                    acc += v0 * __uint_as_float(s0.y) + v1 * __uint_as_float(s1.y)
                         + v2 * __uint_as_float(s2.y) + v3 * __uint_as_float(s3.y)
                         + v4 * __uint_as_float(s4.y) + v5 * __uint_as_float(s5.y)
                         + v6 * __uint_as_float(s6.y) + v7 * __uint_as_float(s7.y);
                }
                for (; j + 4 <= o1; j += 4) {
                    uint2 s0 = bucket[j + 0], s1 = bucket[j + 1];
                    uint2 s2 = bucket[j + 2], s3 = bucket[j + 3];
                    float v0 = bf2f(h1b[(size_t)s0.x * 64 + f]);
                    float v1 = bf2f(h1b[(size_t)s1.x * 64 + f]);
                    float v2 = bf2f(h1b[(size_t)s2.x * 64 + f]);
                    float v3 = bf2f(h1b[(size_t)s3.x * 64 + f]);
                    acc += v0 * __uint_as_float(s0.y) + v1 * __uint_as_float(s1.y)
                         + v2 * __uint_as_float(s2.y) + v3 * __uint_as_float(s3.y);
                }
                for (; j < o1; ++j) {
                    uint2 s = bucket[j];
                    acc += bf2f(h1b[(size_t)s.x * 64 + f]) * __uint_as_float(s.y);
                }
            }
            sagg[g][f] = acc;
            sh[g][f] = hv;
        }
        __syncthreads();
        // phase B: relu dense from packed-bf16 weights
        {
            float sum = sb[f];
            #pragma unroll
            for (int k = 0; k < 32; ++k) {
                unsigned pr = sWrel[f][k], po = sWroot[f][k];
                sum += sagg[g][2 * k]     * bflo(pr)
                     + sagg[g][2 * k + 1] * bfhi(pr)
                     + sh[g][2 * k]       * bflo(po)
                     + sh[g][2 * k + 1]   * bfhi(po);
            }
            sh2[g][f] = fmaxf(sum, 0.f);
        }
        __syncthreads();
        // phase C: fc (40 threads)
        if (tid < 4 * 10) {
            int n2 = tid / 10, c = tid % 10;
            int node = base + n2;
            if (node < N_NODES) {
                float o = sfb[c];
                #pragma unroll
                for (int k = 0; k < 32; ++k) {
                    unsigned pc = sfc[c][k];
                    o += sh2[n2][2 * k] * bflo(pc) + sh2[n2][2 * k + 1] * bfhi(pc);
                }
                out[(size_t)node * 10 + c] = o;
            }
        }
    }
}

extern "C" void kernel_launch(void* const* d_in, const int* in_sizes, int n_in,
                              void* d_out, int out_size, void* d_ws, size_t ws_size,
                              hipStream_t stream) {
    const float* x       = (const float*)d_in[0];
    const int*   ei      = (const int*)d_in[1];     // [2, E] int32
    const float* ew      = (const float*)d_in[2];
    const float* W1_rel  = (const float*)d_in[3];
    const float* b1_rel  = (const float*)d_in[4];
    const float* W1_root = (const float*)d_in[5];
    const float* W2_rel  = (const float*)d_in[6];
    const float* b2_rel  = (const float*)d_in[7];
    const float* W2_root = (const float*)d_in[8];
    const float* fc_w    = (const float*)d_in[9];
    const float* fc_b    = (const float*)d_in[10];
    float* out = (float*)d_out;

    // workspace layout (~27 MB)
    uint2* bucket          = (uint2*)d_ws;                        // E slots (12.8 MB)
    unsigned short* h1b    = (unsigned short*)(bucket + EDGES);   // N*64 bf16 (12.8 MB)
    int*   cnt    = (int*)(h1b + (size_t)N_NODES * 64);           // N
    int*   part   = cnt + N_NODES;                                // N
    int*   offs   = part + N_NODES;                               // N+1
    int*   cursor = offs + N_NODES + 1;                           // N
    int*   bsum   = cursor + N_NODES;                             // 256
    int*   bsumx  = bsum + 256;                                   // 256

    // only the histogram counters need zeroing (ws re-poisoned 0xAA each call)
    hipMemsetAsync(cnt, 0, (size_t)N_NODES * sizeof(int), stream);

    hist_kernel<<<(EDGES + 255) / 256, 256, 0, stream>>>(ei, cnt);
    scan1_kernel<<<SCAN_NB, 512, 0, stream>>>(cnt, part, bsum);
    scan2_kernel<<<1, 256, 0, stream>>>(bsum, bsumx);
    scan3_kernel<<<SCAN_NB, 512, 0, stream>>>(part, bsumx, offs, cursor);
    fill_kernel<<<(EDGES + 255) / 256, 256, 0, stream>>>(ei, ew, cursor, bucket);

    agg_dense1_kernel<<<2048, 256, 0, stream>>>(
        x, bucket, offs, W1_rel, b1_rel, W1_root, h1b);
    agg_dense2_kernel<<<2048, 256, 0, stream>>>(
        h1b, bucket, offs, W2_rel, b2_rel, W2_root, fc_w, fc_b, out);
}